// Round 6
// baseline (62.412 us; speedup 1.0000x reference)
//
#include <hip/hip_runtime.h>

#define K 3

typedef float v4f __attribute__((ext_vector_type(4)));

// Knot value at index j, computed on the fly from sorted x:
// t[0..K]=x[0]; t[j]=(x[j-3]+x[j-2]+x[j-1])/3 for K<j<N; t[j>=N]=x[N-1].
__device__ __forceinline__ float tfun(const float* __restrict__ x, int j, int N) {
    if (j <= K) return x[0];
    if (j >= N) return x[N - 1];
    return (x[j - 3] + x[j - 2] + x[j - 1]) / 3.0f;
}

// Knot interval without binary search: t[i+1] <= x[i] and t[i+4] > x[i], so
// j0 in {i+1,i+2,i+3}; reference's top-edge override/degree clamp = [K, N-1].
__device__ __forceinline__ int j0_of(const float* __restrict__ x, int i, int N) {
    float xi = x[i];
    int j0 = i + 1;
    if (tfun(x, i + 2, N) <= xi) j0 = i + 2;
    if (tfun(x, i + 3, N) <= xi) j0 = i + 3;
    if (j0 > N - 1) j0 = N - 1;
    if (j0 < K) j0 = K;
    return j0;
}

// Windowed Cox-de Boor with safe_div (0-den -> 0) semantics on [j0-K, j0].
__device__ __forceinline__ float4 deboor(const float* __restrict__ x, float xi,
                                         int j0, int N) {
    int c0 = j0 - K;
    float b[K + 2];
    #pragma unroll
    for (int w = 0; w < K + 2; ++w) b[w] = 0.f;
    b[K] = 1.f;
    #pragma unroll
    for (int d = 1; d <= K; ++d) {
        float nb[K + 1];
        #pragma unroll
        for (int w = 0; w <= K; ++w) {
            int j = c0 + w;
            float tj   = tfun(x, j, N);
            float tjd  = tfun(x, j + d, N);
            float tj1  = tfun(x, j + 1, N);
            float tjd1 = tfun(x, j + d + 1, N);
            float denL = tjd - tj;
            float L = (denL == 0.f) ? 0.f : (xi - tj) / denL;
            float denR = tjd1 - tj1;
            float R = (denR == 0.f) ? 0.f : (tjd1 - xi) / denR;
            nb[w] = L * b[w] + R * b[w + 1];
        }
        #pragma unroll
        for (int w = 0; w <= K; ++w) b[w] = nb[w];
    }
    return make_float4(b[0], b[1], b[2], b[3]);
}

#define B1 64
#define HALO 4            // rows below block start; +5 above -> 73 LDS entries

// K1: all precompute in one launch (proven round 4). Thread i: knots, j0[i],
// vals4[i] via LDS share with halo, and band column i of B^T B (+s on diag).
__global__ __launch_bounds__(B1) void k1_precompute(const float* __restrict__ x,
                                                    const float* __restrict__ s_ptr,
                                                    float* __restrict__ out_knots,
                                                    float* __restrict__ vals,
                                                    int* __restrict__ j0arr,
                                                    float* __restrict__ band, int N) {
    __shared__ float4 lv[73];
    __shared__ int lj[73];
    int t = threadIdx.x;
    int bs = blockIdx.x * B1;

    for (int k = t; k < 73; k += B1) {
        int rb = bs - HALO + k;
        if (rb >= 0 && rb < N) {
            int j0 = j0_of(x, rb, N);
            lj[k] = j0;
            lv[k] = deboor(x, x[rb], j0, N);
        } else {
            lj[k] = -1000000;
            lv[k] = make_float4(0.f, 0.f, 0.f, 0.f);
        }
    }
    __syncthreads();

    int i = bs + t;
    if (i >= N) return;

    out_knots[i] = tfun(x, i, N);
    if (i < K + 1) out_knots[N + i] = x[N - 1];

    int kk = t + HALO;
    int j0i = lj[kk];
    j0arr[i] = j0i;
    *(float4*)(vals + 4 * i) = lv[kk];

    float acc[2 * K + 1];
    #pragma unroll
    for (int a = 0; a < 2 * K + 1; ++a) acc[a] = 0.f;

    #pragma unroll
    for (int d = -3; d <= 5; ++d) {               // candidate rows r = i + d
        int k2 = kk + d;
        int j0r = lj[k2];
        if (j0r < i || j0r > i + K) continue;
        float4 w4 = lv[k2];
        int wi = i - (j0r - K);                   // in [0, K]
        float v = (wi == 0) ? w4.x : (wi == 1) ? w4.y : (wi == 2) ? w4.z : w4.w;
        #pragma unroll
        for (int o = -K; o <= K; ++o) {
            int wj = wi + o;
            float w = (wj == 0) ? w4.x : (wj == 1) ? w4.y : (wj == 2) ? w4.z
                    : (wj == 3) ? w4.w : 0.f;
            acc[o + K] += v * w;
        }
    }
    acc[K] += *s_ptr;

    *(float4*)(band + i * 8)     = make_float4(acc[0], acc[1], acc[2], acc[3]);
    *(float4*)(band + i * 8 + 4) = make_float4(acc[4], acc[5], acc[6], 0.f);
}

// K2: fill-structure writer with NON-TEMPORAL stores (bypass write-allocate:
// round-3 counters showed FETCH ~= 3.5x WRITE on a store-only kernel -> RFO).
__global__ __launch_bounds__(256) void k2_fill(const float* __restrict__ vals,
                                               const int* __restrict__ j0arr,
                                               const float* __restrict__ band,
                                               float* __restrict__ outB, int N) {
    int fpr = N >> 2;                       // float4s per row (1024, pow2)
    int shift = __ffs(fpr) - 1;
    int mask = fpr - 1;
    long long total = 2LL * N * fpr;
    long long stride = (long long)gridDim.x * blockDim.x;
    long long g = (long long)blockIdx.x * blockDim.x + threadIdx.x;
    v4f* o4 = (v4f*)outB;

    for (; g < total; g += stride) {
        int f = (int)(g & mask);
        int row = (int)(g >> shift);        // 0..2N-1
        v4f z = {0.f, 0.f, 0.f, 0.f};
        if (row < N) {
            // ---- B row ----
            int c0 = j0arr[row] - K;        // wave-uniform, L1/L2-hot
            int fw0 = c0 >> 2, fw1 = (c0 + K) >> 2;
            if (f == fw0 || f == fw1) {
                float4 v4 = *(const float4*)(vals + row * 4);
                int e0 = f * 4;
                float e[4];
                #pragma unroll
                for (int l = 0; l < 4; ++l) {
                    int d = e0 + l - c0;
                    e[l] = (d == 0) ? v4.x : (d == 1) ? v4.y : (d == 2) ? v4.z
                         : (d == 3) ? v4.w : 0.f;
                }
                z = (v4f){e[0], e[1], e[2], e[3]};
            }
        } else {
            // ---- BTB row ---- (window position needs NO load: ci +/- 3)
            int ci = row - N;
            int wlo = ci - K; if (wlo < 0) wlo = 0;
            int whi = ci + K; if (whi > N - 1) whi = N - 1;
            int fw0 = wlo >> 2, fw1 = whi >> 2;
            if (f >= fw0 && f <= fw1) {
                float4 b0 = *(const float4*)(band + ci * 8);     // offsets -3..0
                float4 b1 = *(const float4*)(band + ci * 8 + 4); // offsets  1..3
                int e0 = f * 4;
                float e[4];
                #pragma unroll
                for (int l = 0; l < 4; ++l) {
                    int d = e0 + l - ci;    // diagonal offset in [-3, 3]
                    e[l] = (d == -3) ? b0.x : (d == -2) ? b0.y : (d == -1) ? b0.z
                         : (d ==  0) ? b0.w : (d ==  1) ? b1.x : (d ==  2) ? b1.y
                         : (d ==  3) ? b1.z : 0.f;
                }
                z = (v4f){e[0], e[1], e[2], e[3]};
            }
        }
        __builtin_nontemporal_store(z, o4 + g);
    }
}

extern "C" void kernel_launch(void* const* d_in, const int* in_sizes, int n_in,
                              void* d_out, int out_size, void* d_ws, size_t ws_size,
                              hipStream_t stream) {
    const float* x = (const float*)d_in[0];
    const float* s = (const float*)d_in[1];
    int N = in_sizes[0];            // 4096
    int nk = N + K + 1;             // 4100

    float* out = (float*)d_out;
    float* out_knots = out;
    float* out_B = out + nk;        // byte offset 16400 -> 16B aligned

    // workspace: band (N*8 f) | vals (N*4 f) | j0 (N i)
    float* band_ws = (float*)d_ws;
    float* vals_ws = band_ws + (long long)N * 8;
    int* j0_ws = (int*)(vals_ws + (long long)N * 4);

    k1_precompute<<<(N + B1 - 1) / B1, B1, 0, stream>>>(x, s, out_knots,
                                                        vals_ws, j0_ws, band_ws, N);
    k2_fill<<<2048, 256, 0, stream>>>(vals_ws, j0_ws, band_ws, out_B, N);
}

// Round 7
// 45.076 us; speedup vs baseline: 1.3846x; 1.3846x over previous
//
#include <hip/hip_runtime.h>

#define K 3

// Knot value at index j, computed on the fly from sorted x:
// t[0..K]=x[0]; t[j]=(x[j-3]+x[j-2]+x[j-1])/3 for K<j<N; t[j>=N]=x[N-1].
__device__ __forceinline__ float tfun(const float* __restrict__ x, int j, int N) {
    if (j <= K) return x[0];
    if (j >= N) return x[N - 1];
    return (x[j - 3] + x[j - 2] + x[j - 1]) / 3.0f;
}

// Knot interval without binary search: t[i+1] <= x[i] and t[i+4] > x[i], so
// j0 in {i+1,i+2,i+3}; reference's top-edge override/degree clamp = [K, N-1].
__device__ __forceinline__ int j0_of(const float* __restrict__ x, int i, int N) {
    float xi = x[i];
    int j0 = i + 1;
    if (tfun(x, i + 2, N) <= xi) j0 = i + 2;
    if (tfun(x, i + 3, N) <= xi) j0 = i + 3;
    if (j0 > N - 1) j0 = N - 1;
    if (j0 < K) j0 = K;
    return j0;
}

// Windowed Cox-de Boor with safe_div (0-den -> 0) semantics on [j0-K, j0].
__device__ __forceinline__ float4 deboor(const float* __restrict__ x, float xi,
                                         int j0, int N) {
    int c0 = j0 - K;
    float b[K + 2];
    #pragma unroll
    for (int w = 0; w < K + 2; ++w) b[w] = 0.f;
    b[K] = 1.f;
    #pragma unroll
    for (int d = 1; d <= K; ++d) {
        float nb[K + 1];
        #pragma unroll
        for (int w = 0; w <= K; ++w) {
            int j = c0 + w;
            float tj   = tfun(x, j, N);
            float tjd  = tfun(x, j + d, N);
            float tj1  = tfun(x, j + 1, N);
            float tjd1 = tfun(x, j + d + 1, N);
            float denL = tjd - tj;
            float L = (denL == 0.f) ? 0.f : (xi - tj) / denL;
            float denR = tjd1 - tj1;
            float R = (denR == 0.f) ? 0.f : (tjd1 - xi) / denR;
            nb[w] = L * b[w] + R * b[w + 1];
        }
        #pragma unroll
        for (int w = 0; w <= K; ++w) b[w] = nb[w];
    }
    return make_float4(b[0], b[1], b[2], b[3]);
}

#define B1 64
#define HALO 4            // rows below block start; +5 above -> 73 LDS entries

// Runs AFTER the bulk memset (stream-ordered). Thread i writes: knots[i]
// (+tail), the 4-float window of B row i, and the 7-float band of BTB row i
// (band accumulated from LDS-shared neighbor de Boor values, +s on diagonal).
// Scattered stores land on freshly-zeroed L2/L3-resident lines (~2 MB total).
__global__ __launch_bounds__(B1) void patch_windows(const float* __restrict__ x,
                                                    const float* __restrict__ s_ptr,
                                                    float* __restrict__ out_knots,
                                                    float* __restrict__ outB,
                                                    float* __restrict__ outBTB, int N) {
    __shared__ float4 lv[73];
    __shared__ int lj[73];
    int t = threadIdx.x;
    int bs = blockIdx.x * B1;

    for (int k = t; k < 73; k += B1) {
        int rb = bs - HALO + k;
        if (rb >= 0 && rb < N) {
            int j0 = j0_of(x, rb, N);
            lj[k] = j0;
            lv[k] = deboor(x, x[rb], j0, N);
        } else {
            lj[k] = -1000000;                 // never passes the window test
            lv[k] = make_float4(0.f, 0.f, 0.f, 0.f);
        }
    }
    __syncthreads();

    int i = bs + t;
    if (i >= N) return;

    out_knots[i] = tfun(x, i, N);
    if (i < K + 1) out_knots[N + i] = x[N - 1];   // knots N..N+K

    int kk = t + HALO;
    int j0i = lj[kk];
    float4 v4i = lv[kk];

    // ---- B row i window: 4 consecutive floats at column j0i-K ----
    float* bp = outB + (long long)i * N + (j0i - K);
    bp[0] = v4i.x; bp[1] = v4i.y; bp[2] = v4i.z; bp[3] = v4i.w;

    // ---- band column i of B^T B: contributing rows r with j0[r] in [i, i+K]
    //      lie in r = i-3 .. i+5 (since j0[r] in {r+1,r+2,r+3} clamped) ----
    float acc[2 * K + 1];
    #pragma unroll
    for (int a = 0; a < 2 * K + 1; ++a) acc[a] = 0.f;

    #pragma unroll
    for (int d = -3; d <= 5; ++d) {               // candidate rows r = i + d
        int k2 = kk + d;                          // in [t+1, t+9] ⊂ [0,73)
        int j0r = lj[k2];
        if (j0r < i || j0r > i + K) continue;     // row doesn't touch column i
        float4 w4 = lv[k2];
        int wi = i - (j0r - K);                   // in [0, K]
        float v = (wi == 0) ? w4.x : (wi == 1) ? w4.y : (wi == 2) ? w4.z : w4.w;
        #pragma unroll
        for (int o = -K; o <= K; ++o) {
            int wj = wi + o;
            float w = (wj == 0) ? w4.x : (wj == 1) ? w4.y : (wj == 2) ? w4.z
                    : (wj == 3) ? w4.w : 0.f;
            acc[o + K] += v * w;                  // static acc index
        }
    }
    acc[K] += *s_ptr;

    // ---- BTB row i: entries at columns i-3..i+3 ----
    long long base = (long long)i * N;
    #pragma unroll
    for (int d = -K; d <= K; ++d) {
        int c = i + d;
        if (c >= 0 && c < N) outBTB[base + c] = acc[d + K];
    }
}

extern "C" void kernel_launch(void* const* d_in, const int* in_sizes, int n_in,
                              void* d_out, int out_size, void* d_ws, size_t ws_size,
                              hipStream_t stream) {
    const float* x = (const float*)d_in[0];
    const float* s = (const float*)d_in[1];
    int N = in_sizes[0];            // 4096
    int nk = N + K + 1;             // 4100

    float* out = (float*)d_out;
    float* out_knots = out;
    float* out_B = out + nk;
    float* out_BTB = out_B + (long long)N * N;

    // Bulk zero via the runtime's fill kernel (proven ~6.8 TB/s in-session).
    // Stream-ordered: the patch kernel below runs after it completes.
    hipMemsetAsync(d_out, 0, (size_t)out_size * sizeof(float), stream);

    patch_windows<<<(N + B1 - 1) / B1, B1, 0, stream>>>(x, s, out_knots,
                                                        out_B, out_BTB, N);
}